// Round 4
// baseline (2470.745 us; speedup 1.0000x reference)
//
#include <hip/hip_runtime.h>
#include <math.h>

#define NROWS 32768
#define DIM   256
#define KCODES 1024

// ws layout (bytes):
//   0       : double loss accumulator (8)
//   16      : se[1024] float
//   4112    : sx[32768] float
//   135184  : best0[32768] float   (half 0: codes 0..511)
//   266256  : best1[32768] float   (half 1: codes 512..1023)
//   397328  : idx0[32768] int
//   528400  : idx1[32768] int

__global__ void init_ws(double* acc) {
    if (threadIdx.x == 0 && blockIdx.x == 0) *acc = 0.0;
}

// Bit-exact replication of numpy pairwise_sum_FLOAT for n=256 contiguous floats
// (sum of squares of each row). 8-acc blocked tree + xor-butterfly combine.
__global__ void rowsq_kernel(const float* __restrict__ src,
                             float* __restrict__ dst, int nrows) {
    const int gtid = blockIdx.x * blockDim.x + threadIdx.x;
    const int wave = gtid >> 6;
    const int lane = threadIdx.x & 63;
    const int rowsub = lane >> 4;
    const int agent  = lane & 15;
    const int half   = agent >> 3;
    const int j      = agent & 7;
    const int row = wave * 4 + rowsub;
    if (row >= nrows) return;

    const float* p = src + (size_t)row * DIM + half * 128 + j;
    float x0 = p[0];
    float r = __fmul_rn(x0, x0);
    #pragma unroll
    for (int i = 1; i < 16; ++i) {
        float xi = p[8 * i];
        r = __fadd_rn(r, __fmul_rn(xi, xi));
    }
    r = __fadd_rn(r, __shfl_xor(r, 1, 64));
    r = __fadd_rn(r, __shfl_xor(r, 2, 64));
    r = __fadd_rn(r, __shfl_xor(r, 4, 64));
    r = __fadd_rn(r, __shfl_xor(r, 8, 64));
    if (agent == 0) dst[row] = r;
}

#define FMA4(A, X, E) do {                                       \
    A.x = fmaf(X.x, E.x, A.x); A.y = fmaf(X.y, E.y, A.y);        \
    A.z = fmaf(X.z, E.z, A.z); A.w = fmaf(X.w, E.w, A.w);        \
} while (0)

// 64 rows x 512 codes per block (codebook split 2-way across blocks).
// 4 passes of 128 codes, K chunked at 64 floats. LDS stride 68 floats ->
// conflict-free reads (R3 measured SQ_LDS_BANK_CONFLICT = 0).
// 52 KB LDS -> 3 blocks/CU (grid 1024 -> occupancy no longer grid-capped).
__launch_bounds__(256, 3)
__global__ void vq_partial(const float* __restrict__ x,
                           const float* __restrict__ cb,
                           const float* __restrict__ sx_arr,
                           const float* __restrict__ se_arr,
                           float* __restrict__ best_out,  // [2][32768]
                           int* __restrict__ idx_out) {   // [2][32768]
    __shared__ __align__(16) float xs[64 * 68];
    __shared__ __align__(16) float cs[128 * 68];
    const int tid = threadIdx.x;
    const int rb  = blockIdx.x >> 1;
    const int ch  = blockIdx.x & 1;
    const int n0  = rb * 64;
    const int cbase = ch * 512;
    const int rg  = tid >> 4;
    const int cg  = tid & 15;
    const float4* __restrict__ x4  = (const float4*)x;
    const float4* __restrict__ cb4 = (const float4*)cb;

    float sx[4], best[4];
    int bidx[4];
    #pragma unroll
    for (int r = 0; r < 4; ++r) {
        sx[r] = sx_arr[n0 + rg * 4 + r];
        best[r] = INFINITY;
        bidx[r] = 0;
    }

    for (int p = 0; p < 4; ++p) {
        float4 acc[4][8];
        #pragma unroll
        for (int r = 0; r < 4; ++r) {
            #pragma unroll
            for (int c = 0; c < 8; ++c) {
                acc[r][c] = make_float4(0.f, 0.f, 0.f, 0.f);
            }
        }

        for (int q = 0; q < 4; ++q) {
            __syncthreads();
            #pragma unroll
            for (int i = 0; i < 4; ++i) {
                int l = i * 256 + tid;
                int row = l >> 4, k4 = l & 15;
                float4 v = x4[(size_t)(n0 + row) * 64 + q * 16 + k4];
                *(float4*)(xs + row * 68 + k4 * 4) = v;
            }
            #pragma unroll
            for (int i = 0; i < 8; ++i) {
                int l = i * 256 + tid;
                int row = l >> 4, k4 = l & 15;
                float4 v = cb4[(size_t)(cbase + p * 128 + row) * 64 + q * 16 + k4];
                *(float4*)(cs + row * 68 + k4 * 4) = v;
            }
            __syncthreads();

            #pragma unroll
            for (int k4 = 0; k4 < 16; ++k4) {
                float4 xv[4], cv[8];
                #pragma unroll
                for (int r = 0; r < 4; ++r) {
                    xv[r] = *(const float4*)(xs + (rg * 4 + r) * 68 + k4 * 4);
                }
                #pragma unroll
                for (int c = 0; c < 8; ++c) {
                    cv[c] = *(const float4*)(cs + (cg + 16 * c) * 68 + k4 * 4);
                }
                #pragma unroll
                for (int r = 0; r < 4; ++r) {
                    #pragma unroll
                    for (int c = 0; c < 8; ++c) {
                        FMA4(acc[r][c], xv[r], cv[c]);
                    }
                }
            }
        }

        // per-pass argmin epilogue: kk ascending for fixed thread, strict-less
        #pragma unroll
        for (int c = 0; c < 8; ++c) {
            const int kk = cbase + p * 128 + cg + 16 * c;
            const float se = se_arr[kk];
            #pragma unroll
            for (int r = 0; r < 4; ++r) {
                float4 a = acc[r][c];
                float dot = (a.x + a.y) + (a.z + a.w);
                float t = __fadd_rn(sx[r], se);
                float dist = __fsub_rn(t, 2.0f * dot);
                if (dist < best[r]) { best[r] = dist; bidx[r] = kk; }
            }
        }
    }

    // cross-cg argmin reduce (within-wave), tie -> lower k
    #pragma unroll
    for (int r = 0; r < 4; ++r) {
        float b = best[r]; int bi = bidx[r];
        #pragma unroll
        for (int off = 1; off < 16; off <<= 1) {
            float vb = __shfl_xor(b, off, 64);
            int   vi = __shfl_xor(bi, off, 64);
            if (vb < b || (vb == b && vi < bi)) { b = vb; bi = vi; }
        }
        best[r] = b; bidx[r] = bi;
    }
    if (cg == 0) {
        #pragma unroll
        for (int r = 0; r < 4; ++r) {
            best_out[ch * NROWS + n0 + rg * 4 + r] = best[r];
            idx_out[ch * NROWS + n0 + rg * 4 + r]  = bidx[r];
        }
    }
}

// Combine halves, gather winning code row, write quantized out + idx + loss.
__launch_bounds__(256)
__global__ void vq_combine(const float* __restrict__ x,
                           const float* __restrict__ cb,
                           const float* __restrict__ best_arr,
                           const int* __restrict__ idx_arr,
                           float* __restrict__ out_q,
                           float* __restrict__ out_idx,
                           double* __restrict__ loss_acc) {
    const int tid = threadIdx.x;
    const int row = blockIdx.x * 16 + (tid >> 4);
    const int c   = tid & 15;
    const float4* __restrict__ x4  = (const float4*)x;
    const float4* __restrict__ cb4 = (const float4*)cb;

    float b0 = best_arr[row];
    float b1 = best_arr[NROWS + row];
    int   i0 = idx_arr[row];
    int   i1 = idx_arr[NROWS + row];
    // numpy first-min: half0 indices all < half1's -> half1 wins only if strictly less
    int bi = (b1 < b0) ? i1 : i0;
    if (c == 0) out_idx[row] = (float)bi;

    const float4* qrow = cb4 + (size_t)bi * 64;
    double lacc = 0.0;
    #pragma unroll
    for (int m = 0; m < 4; ++m) {
        int d4 = c + 16 * m;
        float4 qv = qrow[d4];
        float4 xv = x4[(size_t)row * 64 + d4];
        float dfx = __fsub_rn(qv.x, xv.x);
        float dfy = __fsub_rn(qv.y, xv.y);
        float dfz = __fsub_rn(qv.z, xv.z);
        float dfw = __fsub_rn(qv.w, xv.w);
        float4 o;
        o.x = __fadd_rn(xv.x, dfx);
        o.y = __fadd_rn(xv.y, dfy);
        o.z = __fadd_rn(xv.z, dfz);
        o.w = __fadd_rn(xv.w, dfw);
        lacc += (double)dfx * dfx + (double)dfy * dfy
              + (double)dfz * dfz + (double)dfw * dfw;
        ((float4*)out_q)[(size_t)row * 64 + d4] = o;
    }
    #pragma unroll
    for (int off = 32; off > 0; off >>= 1) {
        lacc += __shfl_down(lacc, off, 64);
    }
    __shared__ double lsh[4];
    if ((tid & 63) == 0) lsh[tid >> 6] = lacc;
    __syncthreads();
    if (tid == 0) {
        double s = lsh[0] + lsh[1] + lsh[2] + lsh[3];
        atomicAdd(loss_acc, s);
    }
}

__global__ void finalize_loss(const double* __restrict__ acc,
                              float* __restrict__ out_loss) {
    if (threadIdx.x == 0 && blockIdx.x == 0)
        *out_loss = (float)(*acc / (double)(NROWS * DIM));
}

extern "C" void kernel_launch(void* const* d_in, const int* in_sizes, int n_in,
                              void* d_out, int out_size, void* d_ws, size_t ws_size,
                              hipStream_t stream) {
    const float* x  = (const float*)d_in[0];
    const float* cb = (const float*)d_in[1];
    float* out      = (float*)d_out;
    float* out_q    = out;                       // 8388608 elements
    float* out_idx  = out + (size_t)NROWS * DIM; // 32768 elements (as float)
    float* out_loss = out_idx + NROWS;           // 1 element

    char* wsb = (char*)d_ws;
    double* acc   = (double*)wsb;
    float* se     = (float*)(wsb + 16);
    float* sx     = (float*)(wsb + 4112);
    float* bests  = (float*)(wsb + 135184);   // [2][32768]
    int*   idxs   = (int*)(wsb + 397328);     // [2][32768]

    init_ws<<<1, 1, 0, stream>>>(acc);
    rowsq_kernel<<<64, 256, 0, stream>>>(cb, se, KCODES);
    rowsq_kernel<<<NROWS / 16, 256, 0, stream>>>(x, sx, NROWS);
    vq_partial<<<(NROWS / 64) * 2, 256, 0, stream>>>(x, cb, sx, se, bests, idxs);
    vq_combine<<<NROWS / 16, 256, 0, stream>>>(x, cb, bests, idxs, out_q, out_idx, acc);
    finalize_loss<<<1, 1, 0, stream>>>(acc, out_loss);
}

// Round 5
// 392.622 us; speedup vs baseline: 6.2929x; 6.2929x over previous
//
#include <hip/hip_runtime.h>
#include <math.h>

#define NROWS 32768
#define DIM   256
#define KCODES 1024

// ws layout (bytes):
//   0       : double loss accumulator (8)
//   16      : se[1024] float
//   4112    : sx[32768] float
//   135184  : best0[32768] float   (half 0: codes 0..511)
//   266256  : best1[32768] float   (half 1: codes 512..1023)
//   397328  : idx0[32768] int
//   528400  : idx1[32768] int

__global__ void init_ws(double* acc) {
    if (threadIdx.x == 0 && blockIdx.x == 0) *acc = 0.0;
}

// Bit-exact replication of numpy pairwise_sum_FLOAT for n=256 contiguous floats
// (sum of squares of each row). 8-acc blocked tree + xor-butterfly combine.
__global__ void rowsq_kernel(const float* __restrict__ src,
                             float* __restrict__ dst, int nrows) {
    const int gtid = blockIdx.x * blockDim.x + threadIdx.x;
    const int wave = gtid >> 6;
    const int lane = threadIdx.x & 63;
    const int rowsub = lane >> 4;
    const int agent  = lane & 15;
    const int half   = agent >> 3;
    const int j      = agent & 7;
    const int row = wave * 4 + rowsub;
    if (row >= nrows) return;

    const float* p = src + (size_t)row * DIM + half * 128 + j;
    float x0 = p[0];
    float r = __fmul_rn(x0, x0);
    #pragma unroll
    for (int i = 1; i < 16; ++i) {
        float xi = p[8 * i];
        r = __fadd_rn(r, __fmul_rn(xi, xi));
    }
    r = __fadd_rn(r, __shfl_xor(r, 1, 64));
    r = __fadd_rn(r, __shfl_xor(r, 2, 64));
    r = __fadd_rn(r, __shfl_xor(r, 4, 64));
    r = __fadd_rn(r, __shfl_xor(r, 8, 64));
    if (agent == 0) dst[row] = r;
}

#define FMA4(A, X, E) do {                                       \
    A.x = fmaf(X.x, E.x, A.x); A.y = fmaf(X.y, E.y, A.y);        \
    A.z = fmaf(X.z, E.z, A.z); A.w = fmaf(X.w, E.w, A.w);        \
} while (0)

// 64 rows x 512 codes per block (codebook split 2-way across blocks, grid 1024).
// 4 passes of 128 codes, K chunked at 64 floats. LDS stride 68 floats ->
// conflict-free reads (R3: SQ_LDS_BANK_CONFLICT = 0). 52224 B LDS -> 3 blocks/CU.
// __launch_bounds__ MUST stay at 2: (256,3) forced VGPR 128->84 and spilled
// acc[4][8] to scratch (R4: 5.3 GB WRITE_SIZE, 2470 us). 128 VGPR allows
// 4 waves/SIMD, so residency is LDS-capped at 3 blocks/CU — no bound needed.
__launch_bounds__(256, 2)
__global__ void vq_partial(const float* __restrict__ x,
                           const float* __restrict__ cb,
                           const float* __restrict__ sx_arr,
                           const float* __restrict__ se_arr,
                           float* __restrict__ best_out,  // [2][32768]
                           int* __restrict__ idx_out) {   // [2][32768]
    __shared__ __align__(16) float xs[64 * 68];
    __shared__ __align__(16) float cs[128 * 68];
    const int tid = threadIdx.x;
    const int rb  = blockIdx.x >> 1;
    const int ch  = blockIdx.x & 1;
    const int n0  = rb * 64;
    const int cbase = ch * 512;
    const int rg  = tid >> 4;
    const int cg  = tid & 15;
    const float4* __restrict__ x4  = (const float4*)x;
    const float4* __restrict__ cb4 = (const float4*)cb;

    float sx[4], best[4];
    int bidx[4];
    #pragma unroll
    for (int r = 0; r < 4; ++r) {
        sx[r] = sx_arr[n0 + rg * 4 + r];
        best[r] = INFINITY;
        bidx[r] = 0;
    }

    for (int p = 0; p < 4; ++p) {
        float4 acc[4][8];
        #pragma unroll
        for (int r = 0; r < 4; ++r) {
            #pragma unroll
            for (int c = 0; c < 8; ++c) {
                acc[r][c] = make_float4(0.f, 0.f, 0.f, 0.f);
            }
        }

        for (int q = 0; q < 4; ++q) {
            __syncthreads();
            #pragma unroll
            for (int i = 0; i < 4; ++i) {
                int l = i * 256 + tid;
                int row = l >> 4, k4 = l & 15;
                float4 v = x4[(size_t)(n0 + row) * 64 + q * 16 + k4];
                *(float4*)(xs + row * 68 + k4 * 4) = v;
            }
            #pragma unroll
            for (int i = 0; i < 8; ++i) {
                int l = i * 256 + tid;
                int row = l >> 4, k4 = l & 15;
                float4 v = cb4[(size_t)(cbase + p * 128 + row) * 64 + q * 16 + k4];
                *(float4*)(cs + row * 68 + k4 * 4) = v;
            }
            __syncthreads();

            #pragma unroll
            for (int k4 = 0; k4 < 16; ++k4) {
                float4 xv[4], cv[8];
                #pragma unroll
                for (int r = 0; r < 4; ++r) {
                    xv[r] = *(const float4*)(xs + (rg * 4 + r) * 68 + k4 * 4);
                }
                #pragma unroll
                for (int c = 0; c < 8; ++c) {
                    cv[c] = *(const float4*)(cs + (cg + 16 * c) * 68 + k4 * 4);
                }
                #pragma unroll
                for (int r = 0; r < 4; ++r) {
                    #pragma unroll
                    for (int c = 0; c < 8; ++c) {
                        FMA4(acc[r][c], xv[r], cv[c]);
                    }
                }
            }
        }

        // per-pass argmin epilogue: kk ascending for fixed thread, strict-less
        #pragma unroll
        for (int c = 0; c < 8; ++c) {
            const int kk = cbase + p * 128 + cg + 16 * c;
            const float se = se_arr[kk];
            #pragma unroll
            for (int r = 0; r < 4; ++r) {
                float4 a = acc[r][c];
                float dot = (a.x + a.y) + (a.z + a.w);
                float t = __fadd_rn(sx[r], se);
                float dist = __fsub_rn(t, 2.0f * dot);
                if (dist < best[r]) { best[r] = dist; bidx[r] = kk; }
            }
        }
    }

    // cross-cg argmin reduce (within-wave), tie -> lower k
    #pragma unroll
    for (int r = 0; r < 4; ++r) {
        float b = best[r]; int bi = bidx[r];
        #pragma unroll
        for (int off = 1; off < 16; off <<= 1) {
            float vb = __shfl_xor(b, off, 64);
            int   vi = __shfl_xor(bi, off, 64);
            if (vb < b || (vb == b && vi < bi)) { b = vb; bi = vi; }
        }
        best[r] = b; bidx[r] = bi;
    }
    if (cg == 0) {
        #pragma unroll
        for (int r = 0; r < 4; ++r) {
            best_out[ch * NROWS + n0 + rg * 4 + r] = best[r];
            idx_out[ch * NROWS + n0 + rg * 4 + r]  = bidx[r];
        }
    }
}

// Combine halves, gather winning code row, write quantized out + idx + loss.
__launch_bounds__(256)
__global__ void vq_combine(const float* __restrict__ x,
                           const float* __restrict__ cb,
                           const float* __restrict__ best_arr,
                           const int* __restrict__ idx_arr,
                           float* __restrict__ out_q,
                           float* __restrict__ out_idx,
                           double* __restrict__ loss_acc) {
    const int tid = threadIdx.x;
    const int row = blockIdx.x * 16 + (tid >> 4);
    const int c   = tid & 15;
    const float4* __restrict__ x4  = (const float4*)x;
    const float4* __restrict__ cb4 = (const float4*)cb;

    float b0 = best_arr[row];
    float b1 = best_arr[NROWS + row];
    int   i0 = idx_arr[row];
    int   i1 = idx_arr[NROWS + row];
    // numpy first-min: half0 indices all < half1's -> half1 wins only if strictly less
    int bi = (b1 < b0) ? i1 : i0;
    if (c == 0) out_idx[row] = (float)bi;

    const float4* qrow = cb4 + (size_t)bi * 64;
    double lacc = 0.0;
    #pragma unroll
    for (int m = 0; m < 4; ++m) {
        int d4 = c + 16 * m;
        float4 qv = qrow[d4];
        float4 xv = x4[(size_t)row * 64 + d4];
        float dfx = __fsub_rn(qv.x, xv.x);
        float dfy = __fsub_rn(qv.y, xv.y);
        float dfz = __fsub_rn(qv.z, xv.z);
        float dfw = __fsub_rn(qv.w, xv.w);
        float4 o;
        o.x = __fadd_rn(xv.x, dfx);
        o.y = __fadd_rn(xv.y, dfy);
        o.z = __fadd_rn(xv.z, dfz);
        o.w = __fadd_rn(xv.w, dfw);
        lacc += (double)dfx * dfx + (double)dfy * dfy
              + (double)dfz * dfz + (double)dfw * dfw;
        ((float4*)out_q)[(size_t)row * 64 + d4] = o;
    }
    #pragma unroll
    for (int off = 32; off > 0; off >>= 1) {
        lacc += __shfl_down(lacc, off, 64);
    }
    __shared__ double lsh[4];
    if ((tid & 63) == 0) lsh[tid >> 6] = lacc;
    __syncthreads();
    if (tid == 0) {
        double s = lsh[0] + lsh[1] + lsh[2] + lsh[3];
        atomicAdd(loss_acc, s);
    }
}

__global__ void finalize_loss(const double* __restrict__ acc,
                              float* __restrict__ out_loss) {
    if (threadIdx.x == 0 && blockIdx.x == 0)
        *out_loss = (float)(*acc / (double)(NROWS * DIM));
}

extern "C" void kernel_launch(void* const* d_in, const int* in_sizes, int n_in,
                              void* d_out, int out_size, void* d_ws, size_t ws_size,
                              hipStream_t stream) {
    const float* x  = (const float*)d_in[0];
    const float* cb = (const float*)d_in[1];
    float* out      = (float*)d_out;
    float* out_q    = out;                       // 8388608 elements
    float* out_idx  = out + (size_t)NROWS * DIM; // 32768 elements (as float)
    float* out_loss = out_idx + NROWS;           // 1 element

    char* wsb = (char*)d_ws;
    double* acc   = (double*)wsb;
    float* se     = (float*)(wsb + 16);
    float* sx     = (float*)(wsb + 4112);
    float* bests  = (float*)(wsb + 135184);   // [2][32768]
    int*   idxs   = (int*)(wsb + 397328);     // [2][32768]

    init_ws<<<1, 1, 0, stream>>>(acc);
    rowsq_kernel<<<64, 256, 0, stream>>>(cb, se, KCODES);
    rowsq_kernel<<<NROWS / 16, 256, 0, stream>>>(x, sx, NROWS);
    vq_partial<<<(NROWS / 64) * 2, 256, 0, stream>>>(x, cb, sx, se, bests, idxs);
    vq_combine<<<NROWS / 16, 256, 0, stream>>>(x, cb, bests, idxs, out_q, out_idx, acc);
    finalize_loss<<<1, 1, 0, stream>>>(acc, out_loss);
}